// Round 1
// baseline (280.974 us; speedup 1.0000x reference)
//
#include <hip/hip_runtime.h>
#include <math.h>

#define NBATCH 32
#define NL     4096
#define NC     8
#define NT     64
#define NTOT   (NBATCH * NL * NC)   // 1,048,576 delta elements

typedef float f32x4 __attribute__((ext_vector_type(4)));

// ---------------------------------------------------------------------------
// Kernel 1: fp64 sum / sumsq of delta, vectorized float4. (unchanged)
// ---------------------------------------------------------------------------
__global__ __launch_bounds__(256) void reduce_kernel(const float* __restrict__ in,
                                                     double* __restrict__ part) {
    __shared__ double sm[256], sm2[256];
    const int tid = threadIdx.x;
    const f32x4* in4 = reinterpret_cast<const f32x4*>(in);
    double s = 0.0, s2 = 0.0;
    for (int g = blockIdx.x * 256 + tid; g < NTOT / 4; g += 256 * 256) {
        const int e = g * 4;
        if ((e & (NL * NC - 1)) >= NC) {
            const f32x4 cur = in4[g];
            const f32x4 prv = in4[g - 2];
            const double d0 = (double)cur.x - (double)prv.x;
            const double d1 = (double)cur.y - (double)prv.y;
            const double d2 = (double)cur.z - (double)prv.z;
            const double d3 = (double)cur.w - (double)prv.w;
            s  += d0 + d1 + d2 + d3;
            s2 += d0 * d0 + d1 * d1 + d2 * d2 + d3 * d3;
        }
    }
    sm[tid] = s; sm2[tid] = s2;
    __syncthreads();
    for (int off = 128; off > 0; off >>= 1) {
        if (tid < off) { sm[tid] += sm[tid + off]; sm2[tid] += sm2[tid + off]; }
        __syncthreads();
    }
    if (tid == 0) {
        part[2 * blockIdx.x]     = sm[0];
        part[2 * blockIdx.x + 1] = sm2[0];
    }
}

// ---------------------------------------------------------------------------
// Kernel 2: reduce partials -> per-t fp64 constants P[t], Q[t]. (unchanged)
// ---------------------------------------------------------------------------
__global__ __launch_bounds__(256) void finalize_kernel(const double* __restrict__ part,
                                                       const float* __restrict__ gamma,
                                                       const float* __restrict__ beta,
                                                       const float* __restrict__ wv,
                                                       const float* __restrict__ bv,
                                                       double2* __restrict__ pq) {
    __shared__ double sm[256], sm2[256];
    __shared__ double sAB[2];
    const int tid = threadIdx.x;
    sm[tid]  = part[2 * tid];
    sm2[tid] = part[2 * tid + 1];
    __syncthreads();
    for (int off = 128; off > 0; off >>= 1) {
        if (tid < off) { sm[tid] += sm[tid + off]; sm2[tid] += sm2[tid + off]; }
        __syncthreads();
    }
    if (tid == 0) {
        const double mean = sm[0] / (double)NTOT;
        const double var  = sm2[0] / (double)NTOT - mean * mean;
        const double inv  = 1.0 / sqrt(var + 1e-5);
        const double A    = inv * (double)gamma[0];
        const double Bc   = (double)beta[0] - mean * A;
        sAB[0] = A;
        sAB[1] = Bc;
    }
    __syncthreads();
    if (tid < NT) {
        const double A  = sAB[0];
        const double Bc = sAB[1];
        const double w  = (double)wv[tid];
        const double b  = (double)bv[tid];
        double2 r;
        r.x = 0.5 * A * w;
        r.y = 0.5 * (Bc * w + b);
        pq[tid] = r;
    }
}

// ---------------------------------------------------------------------------
// Kernel 3 (R7): bit-packed spike accumulation, phase-split stores.
//  - fp64 LIF math IDENTICAL to R6 (fma(v,0.5,fma(d,P,Q)); vv>=1.0; hard
//    reset) -> same binary decisions, absmax stays 0.0.
//  - Compute phase records spikes as bits (m = 2m + s) in registers; no
//    global stores interleaved with the fp64 recurrence.
//  - Store phase: one float4 (16B/lane) store per t -> 1 KiB/wave bursts,
//    8 KiB contiguous per block per t (vs 512B/wave, 2KiB/block in R6).
//    Theory: R6's ~2.6 TB/s effective write rate is DRAM-locality-bound
//    from 64K interleaved small write streams; dense bursts fix it.
//  - [compute A][store A][compute B][store B]: A-stores drain under the
//    B-compute; only 4 mask regs live at once.
//  - PLAIN stores: nontemporal regressed +11 µs in R3 AND R5. Do not
//    reintroduce.
//  - 512 blocks x 512 threads: 2-4 blocks/CU so compute/store phases of
//    different blocks overlap on each CU.
// ---------------------------------------------------------------------------
__global__ __launch_bounds__(512) void lif_kernel(const float* __restrict__ in,
                                                  const double2* __restrict__ pq,
                                                  float* __restrict__ out) {
    __shared__ __align__(16) double2 spq[NT];
    const int tid = threadIdx.x;
    if (tid < NT) spq[tid] = pq[tid];
    __syncthreads();

    const int blk  = blockIdx.x;       // 512 blocks = B(32) * C(8) * half(2)
    const int half = blk & 1;
    const int c    = (blk >> 1) & 7;
    const int b    = blk >> 4;
    const int l    = half * 2048 + tid * 4;   // 4 consecutive neurons/thread

    // 5 scalar loads for 4 deltas (input is L2/L3-hot after reduce_kernel).
    const float* base = in + (b * NL + l) * NC + c;
    const float xm = (l == 0) ? 0.0f : base[-NC];
    const float x0 = base[0];
    const float x1 = base[NC];
    const float x2 = base[2 * NC];
    const float x3 = base[3 * NC];

    const double d0 = (l == 0) ? 0.0 : ((double)x0 - (double)xm);
    const double d1 = (double)x1 - (double)x0;
    const double d2 = (double)x2 - (double)x1;
    const double d3 = (double)x3 - (double)x2;

    double v0 = 0.0, v1 = 0.0, v2 = 0.0, v3 = 0.0;

    float4* op = reinterpret_cast<float4*>(out + ((b * NT) * NC + c) * NL + l);
    const int tstride = NC * NL / 4;   // 8192 float4 between t-slabs

    // ---- compute A: t = 0..31, spike bits -> mA* (bit for t at pos 31-t) ----
    unsigned mA0 = 0, mA1 = 0, mA2 = 0, mA3 = 0;
#pragma unroll 8
    for (int t = 0; t < 32; ++t) {
        const double2 PQ = spq[t];
        double vv; bool s;
        vv = fma(v0, 0.5, fma(d0, PQ.x, PQ.y)); s = vv >= 1.0; mA0 = mA0 + mA0 + (s ? 1u : 0u); v0 = s ? 0.0 : vv;
        vv = fma(v1, 0.5, fma(d1, PQ.x, PQ.y)); s = vv >= 1.0; mA1 = mA1 + mA1 + (s ? 1u : 0u); v1 = s ? 0.0 : vv;
        vv = fma(v2, 0.5, fma(d2, PQ.x, PQ.y)); s = vv >= 1.0; mA2 = mA2 + mA2 + (s ? 1u : 0u); v2 = s ? 0.0 : vv;
        vv = fma(v3, 0.5, fma(d3, PQ.x, PQ.y)); s = vv >= 1.0; mA3 = mA3 + mA3 + (s ? 1u : 0u); v3 = s ? 0.0 : vv;
    }

    // ---- store A: MSB-first replay of t = 0..31 ----
#pragma unroll 8
    for (int t = 0; t < 32; ++t) {
        float4 o;
        o.x = ((int)mA0 < 0) ? 1.0f : 0.0f; mA0 <<= 1;
        o.y = ((int)mA1 < 0) ? 1.0f : 0.0f; mA1 <<= 1;
        o.z = ((int)mA2 < 0) ? 1.0f : 0.0f; mA2 <<= 1;
        o.w = ((int)mA3 < 0) ? 1.0f : 0.0f; mA3 <<= 1;
        op[t * tstride] = o;
    }

    // ---- compute B: t = 32..63 ----
    unsigned mB0 = 0, mB1 = 0, mB2 = 0, mB3 = 0;
#pragma unroll 8
    for (int t = 32; t < 64; ++t) {
        const double2 PQ = spq[t];
        double vv; bool s;
        vv = fma(v0, 0.5, fma(d0, PQ.x, PQ.y)); s = vv >= 1.0; mB0 = mB0 + mB0 + (s ? 1u : 0u); v0 = s ? 0.0 : vv;
        vv = fma(v1, 0.5, fma(d1, PQ.x, PQ.y)); s = vv >= 1.0; mB1 = mB1 + mB1 + (s ? 1u : 0u); v1 = s ? 0.0 : vv;
        vv = fma(v2, 0.5, fma(d2, PQ.x, PQ.y)); s = vv >= 1.0; mB2 = mB2 + mB2 + (s ? 1u : 0u); v2 = s ? 0.0 : vv;
        vv = fma(v3, 0.5, fma(d3, PQ.x, PQ.y)); s = vv >= 1.0; mB3 = mB3 + mB3 + (s ? 1u : 0u); v3 = s ? 0.0 : vv;
    }

    // ---- store B: t = 32..63 ----
#pragma unroll 8
    for (int t = 32; t < 64; ++t) {
        float4 o;
        o.x = ((int)mB0 < 0) ? 1.0f : 0.0f; mB0 <<= 1;
        o.y = ((int)mB1 < 0) ? 1.0f : 0.0f; mB1 <<= 1;
        o.z = ((int)mB2 < 0) ? 1.0f : 0.0f; mB2 <<= 1;
        o.w = ((int)mB3 < 0) ? 1.0f : 0.0f; mB3 <<= 1;
        op[t * tstride] = o;
    }
}

extern "C" void kernel_launch(void* const* d_in, const int* in_sizes, int n_in,
                              void* d_out, int out_size, void* d_ws, size_t ws_size,
                              hipStream_t stream) {
    const float* inputs = (const float*)d_in[0];   // [B, L, C]
    const float* gamma  = (const float*)d_in[1];   // [1]
    const float* beta   = (const float*)d_in[2];   // [1]
    const float* enc_w  = (const float*)d_in[3];   // [T, 1]
    const float* enc_b  = (const float*)d_in[4];   // [T]
    float* out = (float*)d_out;                    // [B, T, C, L]

    double*  part = (double*)d_ws;                 // 512 doubles (256 blocks x 2)
    double2* pq   = (double2*)(part + 512);        // 64 double2 {P, Q}

    reduce_kernel  <<<256, 256, 0, stream>>>(inputs, part);
    finalize_kernel<<<1,   256, 0, stream>>>(part, gamma, beta, enc_w, enc_b, pq);
    lif_kernel     <<<512, 512, 0, stream>>>(inputs, pq, out);
}